// Round 18
// baseline (535.528 us; speedup 1.0000x reference)
//
#include <hip/hip_runtime.h>
#include <stdint.h>

// ---------------- problem constants ----------------
static constexpr int    N_NODES = 50000;
static constexpr int    N_EDGES = 800000;
static constexpr int    DIN     = 512;
static constexpr int    DOUT    = 128;
static constexpr size_t SEQ_ELEMS = (size_t)N_NODES * DIN;   // 25,600,000
static constexpr size_t H_ELEMS   = (size_t)N_NODES * DOUT;  //  6,400,000

static constexpr int RS_NB = 49;          // 49 keygen/scatter tiles x 1024
static constexpr int EDGE_BLOCKS = 782;   // ceil(800000/1024)
static_assert(N_NODES % 8 == 0, "gather grid assumes 8 nodes/block exactly");

typedef __attribute__((ext_vector_type(8))) short bf16x8;
typedef __attribute__((ext_vector_type(4))) float f32x4;
typedef __attribute__((ext_vector_type(4))) unsigned short u16x4;
typedef __attribute__((ext_vector_type(8))) unsigned short u16x8;

// ---------------- workspace layout (u32 word offsets) ----------------
static constexpr size_t W_HDR    = 0;         // 16 (keys at [4..7])
static constexpr size_t W_DEGCNT = 16;        // 50000
static constexpr size_t W_CURSOR = 50016;     // 50000
static constexpr size_t W_SUMBUF = 100016;    // 128 (float)
static constexpr size_t W_CNT    = 100144;    // 8 (cnt[3]=colsum tail)
static constexpr size_t W_ZEND   = 100152;
static constexpr size_t W_ROWPTR = 175416;    // 50001 (+pad)
static constexpr size_t W_COLSRC = 225420;    // 800000
static constexpr size_t W_DINV   = 1025420;   // 50000 (float)
static constexpr size_t W_KEYS   = 1075420;   // per sort s: keys_in +s*100000, bucket-keys +s*100000+50000
static constexpr size_t W_VALS   = 1275420;   // per sort s: bucket-vals +s*50000
static constexpr size_t W_RANK   = 1475420;   // rank[s][50000]
static constexpr size_t W_BT     = 1625420;   // 128x512 bf16 = 32768 u32 (16B aligned)
static constexpr size_t W_HWI    = 1658188;   // interleaved hw: [50000][256] bf16
static constexpr size_t W_BHIST  = 8058188;   // 2 x 65536 bucket hist
static constexpr size_t W_BOFF   = 8189260;   // 2 x 65536 bucket start (preserved)
static constexpr size_t W_BCUR   = 8320332;   // 2 x 65536 bucket cursor (ticketed)

// ---------------- helpers ----------------
__device__ __forceinline__ uint16_t f2bf(float f) {
  uint32_t u = __float_as_uint(f);
  return (uint16_t)((u + 0x7FFFu + ((u >> 16) & 1u)) >> 16);
}
__device__ __forceinline__ float b2f(uint16_t h) {
  return __uint_as_float(((uint32_t)h) << 16);
}
__device__ __forceinline__ uint32_t rotl32(uint32_t x, int r) {
  return (x << r) | (x >> (32 - r));
}

__device__ __forceinline__ void threefry2x32(uint32_t k0, uint32_t k1,
                                             uint32_t x0, uint32_t x1,
                                             uint32_t& o0, uint32_t& o1) {
  uint32_t ks0 = k0, ks1 = k1, ks2 = k0 ^ k1 ^ 0x1BD11BDAu;
  x0 += ks0; x1 += ks1;
#define TF_ROUND(r) { x0 += x1; x1 = rotl32(x1, (r)); x1 ^= x0; }
  TF_ROUND(13) TF_ROUND(15) TF_ROUND(26) TF_ROUND(6)
  x0 += ks1; x1 += ks2 + 1u;
  TF_ROUND(17) TF_ROUND(29) TF_ROUND(16) TF_ROUND(24)
  x0 += ks2; x1 += ks0 + 2u;
  TF_ROUND(13) TF_ROUND(15) TF_ROUND(26) TF_ROUND(6)
  x0 += ks0; x1 += ks1 + 3u;
  TF_ROUND(17) TF_ROUND(29) TF_ROUND(16) TF_ROUND(24)
  x0 += ks1; x1 += ks2 + 4u;
  TF_ROUND(13) TF_ROUND(15) TF_ROUND(26) TF_ROUND(6)
  x0 += ks2; x1 += ks0 + 5u;
#undef TF_ROUND
  o0 = x0; o1 = x1;
}

__device__ __forceinline__ uint32_t randbits32(uint32_t k0, uint32_t k1, uint32_t ctr) {
  uint32_t a, b;
  threefry2x32(k0, k1, 0u, ctr, a, b);
  return a ^ b;
}

// ---------------- init: zero accumulators + bucket hists + keys + W->BT ----------------
__global__ void __launch_bounds__(256) wt_init_kernel(const float* __restrict__ W,
                                                      uint32_t* __restrict__ wsu) {
  {
    int gid = blockIdx.x * 256 + threadIdx.x;  // 4096 threads
    for (size_t i = W_DEGCNT + gid; i < W_ZEND; i += 4096) wsu[i] = 0u;
    for (size_t i = W_BHIST + gid; i < W_BHIST + 131072; i += 4096) wsu[i] = 0u;
  }
  if (blockIdx.x == 0 && threadIdx.x == 0) {
    uint32_t k3a, k3b, ra, rb, s1a, s1b, s2a, s2b;
    threefry2x32(0u, 1u, 0u, 2u, k3a, k3b);   // split(key(1),3)[2]
    threefry2x32(k3a, k3b, 0u, 0u, ra, rb);   // round1 carry key
    threefry2x32(k3a, k3b, 0u, 1u, s1a, s1b); // round1 subkey
    threefry2x32(ra, rb, 0u, 1u, s2a, s2b);   // round2 subkey
    wsu[4] = s1a; wsu[5] = s1b; wsu[6] = s2a; wsu[7] = s2b;
  }
  uint16_t* BT = (uint16_t*)(wsu + W_BT);
  __shared__ float tile[32][129];
  int k0 = blockIdx.x * 32;
  int t = threadIdx.x;
  for (int i = t; i < 32 * 128; i += 256) {
    int k = i >> 7, n = i & 127;
    tile[k][n] = W[(size_t)(k0 + k) * DOUT + n];
  }
  __syncthreads();
  for (int i = t; i < 32 * 128; i += 256) {
    int n = i >> 5, k = i & 31;
    BT[(size_t)n * DIN + k0 + k] = f2bf(tile[k][n]);
  }
}

// ---------------- fusedA: degree count + keygen/bucket-hist for both sorts ----------------
__global__ void __launch_bounds__(1024) fusedA_kernel(const int* __restrict__ ei,
                                                      uint32_t* __restrict__ wsu) {
  int b = blockIdx.x;
  if (b < EDGE_BLOCKS) {
    int e = b * 1024 + threadIdx.x;
    if (e < N_EDGES) atomicAdd(&wsu[W_DEGCNT + ei[N_EDGES + e]], 1u);
  } else {
    int sb = b - EDGE_BLOCKS, s = sb / RS_NB, bb = sb % RS_NB;
    int p = bb * 1024 + threadIdx.x;
    if (p < N_NODES) {
      uint32_t kv = randbits32(wsu[4 + 2 * s], wsu[5 + 2 * s], (uint32_t)p);
      wsu[W_KEYS + (size_t)s * 100000 + p] = kv;
      atomicAdd(&wsu[W_BHIST + (size_t)s * 65536 + (kv >> 16)], 1u);
    }
  }
}

// ---------------- fusedB: csr scan+dinv (b0) + bucket scans (b1,b2) ----------------
__global__ void __launch_bounds__(1024) fusedB_kernel(uint32_t* __restrict__ wsu) {
  __shared__ uint32_t sc[1024];
  int b = blockIdx.x, t = threadIdx.x;
  if (b == 0) {
    int c0 = t * 49, c1 = c0 + 49;
    if (c0 > N_NODES) c0 = N_NODES;
    if (c1 > N_NODES) c1 = N_NODES;
    float* dinv = (float*)(wsu + W_DINV);
    uint32_t sum = 0;
    for (int c = c0; c < c1; ++c) {
      uint32_t v = wsu[W_DEGCNT + c];
      dinv[c] = __frsqrt_rn((float)(v + 1u));
      sum += v;
    }
    sc[t] = sum;
    __syncthreads();
    for (int off = 1; off < 1024; off <<= 1) {
      uint32_t xx = (t >= off) ? sc[t - off] : 0u;
      __syncthreads();
      sc[t] += xx;
      __syncthreads();
    }
    uint32_t run = sc[t] - sum;
    for (int c = c0; c < c1; ++c) {
      uint32_t h = wsu[W_DEGCNT + c];
      wsu[W_ROWPTR + c] = run;
      run += h;
    }
    if (t == 0) wsu[W_ROWPTR + N_NODES] = (uint32_t)N_EDGES;
  } else {
    int s = b - 1;
    const uint32_t* bh = wsu + W_BHIST + (size_t)s * 65536;
    uint32_t* boff = wsu + W_BOFF + (size_t)s * 65536;
    uint32_t* bcur = wsu + W_BCUR + (size_t)s * 65536;
    int c0 = t * 64;
    uint32_t sum = 0;
    for (int j = 0; j < 64; ++j) sum += bh[c0 + j];
    sc[t] = sum;
    __syncthreads();
    for (int off = 1; off < 1024; off <<= 1) {
      uint32_t xx = (t >= off) ? sc[t - off] : 0u;
      __syncthreads();
      sc[t] += xx;
      __syncthreads();
    }
    uint32_t run = sc[t] - sum;
    for (int j = 0; j < 64; ++j) {
      uint32_t h = bh[c0 + j];
      boff[c0 + j] = run;
      bcur[c0 + j] = run;
      run += h;
    }
  }
}

// ---------------- fusedC: CSR fill + ticket-scatter into buckets ----------------
__global__ void __launch_bounds__(1024) fusedC_kernel(const int* __restrict__ ei,
                                                      uint32_t* __restrict__ wsu) {
  int b = blockIdx.x;
  if (b < EDGE_BLOCKS) {
    int e = b * 1024 + threadIdx.x;
    if (e < N_EDGES) {
      int src = ei[e], dst = ei[N_EDGES + e];
      uint32_t pos = wsu[W_ROWPTR + dst] + atomicAdd(&wsu[W_CURSOR + dst], 1u);
      wsu[W_COLSRC + pos] = (uint32_t)src;
    }
  } else {
    int sb = b - EDGE_BLOCKS, s = sb / RS_NB, bb = sb % RS_NB;
    int p = bb * 1024 + threadIdx.x;
    if (p < N_NODES) {
      uint32_t kv = wsu[W_KEYS + (size_t)s * 100000 + p];
      uint32_t pos = atomicAdd(&wsu[W_BCUR + (size_t)s * 65536 + (kv >> 16)], 1u);
      if (pos < (uint32_t)N_NODES) {
        wsu[W_KEYS + (size_t)s * 100000 + 50000 + pos] = kv;  // bucket keys
        wsu[W_VALS + (size_t)s * 50000 + pos] = (uint32_t)p;  // bucket vals
      }
    }
  }
}

// ---------------- rank: per-bucket (key,idx) compare -> exact stable ranks ----------------
__global__ void __launch_bounds__(1024) rank_kernel(uint32_t* __restrict__ wsu) {
  int gid = blockIdx.x * 1024 + threadIdx.x;  // 131072 threads = 2 x 65536 buckets
  int s = gid >> 16;
  int bkt = gid & 65535;
  uint32_t start = wsu[W_BOFF + (size_t)s * 65536 + bkt];
  uint32_t end   = wsu[W_BCUR + (size_t)s * 65536 + bkt];
  if (end > (uint32_t)N_NODES) end = (uint32_t)N_NODES;
  if (end <= start) return;
  uint32_t c = end - start;
  if (c > 64u) c = 64u;  // defensive cap
  const uint32_t* bk = wsu + W_KEYS + (size_t)s * 100000 + 50000;
  const uint32_t* bv = wsu + W_VALS + (size_t)s * 50000;
  uint32_t* rank = wsu + W_RANK + (size_t)s * 50000;
  for (uint32_t i = 0; i < c; ++i) {
    uint32_t ki = bk[start + i], vi = bv[start + i];
    uint32_t rib = 0;
    for (uint32_t j = 0; j < c; ++j) {
      uint32_t kj = bk[start + j], vj = bv[start + j];
      rib += (kj < ki) || (kj == ki && vj < vi);
    }
    if (vi < (uint32_t)N_NODES && start + rib < (uint32_t)N_NODES)
      rank[vi] = start + rib;
  }
}

// ---------------- fused dropout + MFMA bf16 GEMM (BM=128, swizzled LDS, NT seq) -------
// hwI row: [node][0..127]=pos, [node][128..255]=neg (bf16), scaled by dinv[slot];
// neg slot = rank2[rank1[row]].
__global__ void __launch_bounds__(256) dg_kernel(const float* __restrict__ x,
                                                 const uint16_t* __restrict__ BT,
                                                 const float* __restrict__ pprob,
                                                 const float* __restrict__ dinv,
                                                 const uint32_t* __restrict__ rankA,
                                                 const uint32_t* __restrict__ rankB,
                                                 float* __restrict__ seq_pos,
                                                 float* __restrict__ seq_neg,
                                                 uint16_t* __restrict__ hwI, int M) {
  __shared__ __align__(16) uint16_t ldsA[128 * 64];
  __shared__ __align__(16) uint16_t ldsB[128 * 64];
  const int which = blockIdx.y;
  float* seq = which ? seq_neg : seq_pos;

  uint32_t kk0, kk1;
  threefry2x32(0u, 1u, 0u, (uint32_t)which, kk0, kk1);  // split(key(1),3)[which]
  const float p = pprob[0];
  const float keep_p = 1.0f - p;
  const float scale  = 1.0f / keep_p;
  uint32_t Tint = (uint32_t)ceilf(keep_p * 8388608.0f);
  uint32_t Tu = (Tint >= (1u << 23)) ? 0xFFFFFFFFu : (Tint << 9);

  const int tid  = threadIdx.x;
  const int lane = tid & 63;
  const int w    = tid >> 6;
  const int wr   = w >> 1, wc = w & 1;   // 2x2 wave grid; wave tile 64 rows x 64 cols
  const int m0   = blockIdx.x * 128;
  const int l15  = lane & 15, l4 = lane >> 4;
  const int lr   = lane >> 3;
  const int lk_swz = (((lane & 7) ^ (lane >> 3)) * 8);  // pre-swizzled source block

  f32x4 acc[4][4] = {};

  for (int k0 = 0; k0 < DIN; k0 += 64) {
    // B tile first (pinned oldest in vmcnt order); source pre-swizzled per lane.
#pragma unroll
    for (int s = 0; s < 4; ++s) {
      int nbase = w * 32 + s * 8;  // nbase % 8 == 0 -> row&7 == lane>>3
      const uint16_t* gp = BT + (size_t)(nbase + lr) * DIN + k0 + lk_swz;
      __builtin_amdgcn_global_load_lds(
          (const __attribute__((address_space(1))) void*)gp,
          (__attribute__((address_space(3))) void*)(ldsB + nbase * 64), 16, 0, 0);
    }
    __builtin_amdgcn_sched_barrier(0);  // keep B-loads the 4 oldest VMEM ops
    // A tile: 128 rows x 64 cols -> 8 float4 iters/thread
#pragma unroll
    for (int i = 0; i < 8; ++i) {
      int idx = tid + i * 256;
      int row = idx >> 4, q = idx & 15;
      int grow = m0 + row;
      int crow = (grow < M) ? grow : (M - 1);  // tail rows duplicate row M-1 (benign)
      float4 v = *reinterpret_cast<const float4*>(x + (size_t)crow * DIN + k0 + q * 4);
      float r[4] = {v.x, v.y, v.z, v.w};
      uint32_t cbase = (uint32_t)crow * DIN + k0 + q * 4;
#pragma unroll
      for (int j = 0; j < 4; ++j) {
        uint32_t bits = randbits32(kk0, kk1, cbase + j);
        r[j] = (bits < Tu) ? r[j] * scale : 0.0f;
      }
      f32x4 rv;
      rv.x = r[0]; rv.y = r[1]; rv.z = r[2]; rv.w = r[3];
      __builtin_nontemporal_store(rv,
          reinterpret_cast<f32x4*>(seq + (size_t)crow * DIN + k0 + q * 4));
      uint32_t u0 = __float_as_uint(r[0]), u1 = __float_as_uint(r[1]);
      uint32_t lo = (u0 >> 16) | (u1 & 0xFFFF0000u);
      u0 = __float_as_uint(r[2]); u1 = __float_as_uint(r[3]);
      uint32_t hi = (u0 >> 16) | (u1 & 0xFFFF0000u);
      int sblk = (q >> 1) ^ (row & 7);
      *reinterpret_cast<uint2*>(&ldsA[row * 64 + sblk * 8 + (q & 1) * 4]) = make_uint2(lo, hi);
    }
    asm volatile("s_waitcnt vmcnt(8) lgkmcnt(0)" ::: "memory");
    __builtin_amdgcn_s_barrier();
    __builtin_amdgcn_sched_barrier(0);  // rule #18: no hoisting above the barrier
#pragma unroll
    for (int kk = 0; kk < 2; ++kk) {
      bf16x8 afr[4], bfr[4];
#pragma unroll
      for (int f = 0; f < 4; ++f) {
        int ra = wr * 64 + f * 16 + l15;
        int bp = (kk * 4 + l4) ^ (ra & 7);
        afr[f] = *reinterpret_cast<const bf16x8*>(ldsA + ra * 64 + bp * 8);
      }
#pragma unroll
      for (int f = 0; f < 4; ++f) {
        int rb = wc * 64 + f * 16 + l15;
        int bp = (kk * 4 + l4) ^ (rb & 7);
        bfr[f] = *reinterpret_cast<const bf16x8*>(ldsB + rb * 64 + bp * 8);
      }
#pragma unroll
      for (int fm = 0; fm < 4; ++fm)
#pragma unroll
        for (int fn = 0; fn < 4; ++fn)
          acc[fm][fn] = __builtin_amdgcn_mfma_f32_16x16x32_bf16(afr[fm], bfr[fn], acc[fm][fn], 0, 0, 0);
    }
    __builtin_amdgcn_s_barrier();  // LDS reuse guard
  }
#pragma unroll
  for (int fm = 0; fm < 4; ++fm) {
#pragma unroll
    for (int r = 0; r < 4; ++r) {
      int row = m0 + wr * 64 + fm * 16 + l4 * 4 + r;
      if (row < M) {
        uint32_t slot = (uint32_t)row;
        if (which) {
          uint32_t r1 = rankA[row];
          slot = (r1 < (uint32_t)N_NODES) ? rankB[r1] : 0u;
          if (slot >= (uint32_t)N_NODES) slot = 0u;
        }
        float sc = dinv[slot];
        uint16_t* cp = hwI + (size_t)slot * 256 + which * 128 + wc * 64 + l15;
#pragma unroll
        for (int fn = 0; fn < 4; ++fn)
          cp[fn * 16] = f2bf(acc[fm][fn][r] * sc);
      }
    }
  }
}

// ---------------- gather conv: interleaved hwI rows, 16B/lane, 8-edge unroll ----------
__global__ void __launch_bounds__(256) gcn_gather_kernel(const uint16_t* __restrict__ hwI,
                                                         const float* __restrict__ dinv,
                                                         const uint32_t* __restrict__ rowptr,
                                                         const uint32_t* __restrict__ colsrc,
                                                         const float* __restrict__ bias,
                                                         float* __restrict__ out_pos,
                                                         float* __restrict__ out_neg) {
  const int t = threadIdx.x;
  int node = blockIdx.x * 8 + (t >> 5);  // N_NODES % 8 == 0
  int lane32 = t & 31;
  int c8 = (lane32 & 15) * 8;
  int half = lane32 >> 4;                // 0 = pos, 1 = neg
  uint32_t e0 = rowptr[node], e1 = rowptr[node + 1];
  float a0 = 0.f, a1 = 0.f, a2 = 0.f, a3 = 0.f, a4 = 0.f, a5 = 0.f, a6 = 0.f, a7 = 0.f;
  uint32_t e = e0;
  for (; e + 8 <= e1; e += 8) {
    uint32_t ss[8];
#pragma unroll
    for (int j = 0; j < 8; ++j) ss[j] = colsrc[e + j];
    u16x8 vv[8];
#pragma unroll
    for (int j = 0; j < 8; ++j)
      vv[j] = *reinterpret_cast<const u16x8*>(hwI + (size_t)ss[j] * 256 + lane32 * 8);
#pragma unroll
    for (int j = 0; j < 8; ++j) {
      a0 += b2f(vv[j][0]); a1 += b2f(vv[j][1]); a2 += b2f(vv[j][2]); a3 += b2f(vv[j][3]);
      a4 += b2f(vv[j][4]); a5 += b2f(vv[j][5]); a6 += b2f(vv[j][6]); a7 += b2f(vv[j][7]);
    }
  }
  for (; e < e1; ++e) {
    uint32_t s = colsrc[e];
    u16x8 v = *reinterpret_cast<const u16x8*>(hwI + (size_t)s * 256 + lane32 * 8);
    a0 += b2f(v[0]); a1 += b2f(v[1]); a2 += b2f(v[2]); a3 += b2f(v[3]);
    a4 += b2f(v[4]); a5 += b2f(v[5]); a6 += b2f(v[6]); a7 += b2f(v[7]);
  }
  u16x8 sv = *reinterpret_cast<const u16x8*>(hwI + (size_t)node * 256 + lane32 * 8);
  float dn = dinv[node];
  float4 b0 = *reinterpret_cast<const float4*>(bias + c8);
  float4 b1 = *reinterpret_cast<const float4*>(bias + c8 + 4);
  f32x4 o0, o1;
  o0.x = fmaxf(dn * (a0 + b2f(sv[0])) + b0.x, 0.0f);
  o0.y = fmaxf(dn * (a1 + b2f(sv[1])) + b0.y, 0.0f);
  o0.z = fmaxf(dn * (a2 + b2f(sv[2])) + b0.z, 0.0f);
  o0.w = fmaxf(dn * (a3 + b2f(sv[3])) + b0.w, 0.0f);
  o1.x = fmaxf(dn * (a4 + b2f(sv[4])) + b1.x, 0.0f);
  o1.y = fmaxf(dn * (a5 + b2f(sv[5])) + b1.y, 0.0f);
  o1.z = fmaxf(dn * (a6 + b2f(sv[6])) + b1.z, 0.0f);
  o1.w = fmaxf(dn * (a7 + b2f(sv[7])) + b1.w, 0.0f);
  float* dst = (half ? out_neg : out_pos) + (size_t)node * DOUT + c8;
  if (half) {
    __builtin_nontemporal_store(o0, reinterpret_cast<f32x4*>(dst));
    __builtin_nontemporal_store(o1, reinterpret_cast<f32x4*>(dst + 4));
  } else {
    *reinterpret_cast<f32x4*>(dst)     = o0;
    *reinterpret_cast<f32x4*>(dst + 4) = o1;
  }
}

// ---------------- summary: colsum (196 blocks) + last-block sigmoid ----------------
__global__ void __launch_bounds__(128) colsum_sig_kernel(const float* __restrict__ ph,
                                                         float* __restrict__ sumbuf,
                                                         uint32_t* __restrict__ counter,
                                                         float* __restrict__ outs) {
  int c = threadIdx.x;  // 0..127
  int r0 = blockIdx.x * 256;
  int r1 = r0 + 256; if (r1 > N_NODES) r1 = N_NODES;
  float s = 0.0f;
  for (int r = r0; r < r1; ++r) s += ph[(size_t)r * DOUT + c];
  atomicAdd(&sumbuf[c], s);
  __threadfence();
  __syncthreads();
  __shared__ uint32_t lastflag;
  if (c == 0) lastflag = atomicAdd(counter, 1u);
  __syncthreads();
  if (lastflag == gridDim.x - 1) {
    __threadfence();
    float m = atomicAdd(&sumbuf[c], 0.0f) * (1.0f / (float)N_NODES);
    outs[c] = 1.0f / (1.0f + expf(-m));
  }
}

// ---------------- launch ----------------
extern "C" void kernel_launch(void* const* d_in, const int* in_sizes, int n_in,
                              void* d_out, int out_size, void* d_ws, size_t ws_size,
                              hipStream_t stream) {
  const float* x     = (const float*)d_in[0];
  const int*   ei    = (const int*)d_in[1];
  const float* W     = (const float*)d_in[2];
  const float* bias  = (const float*)d_in[3];
  const float* pprob = (const float*)d_in[4];

  float* out = (float*)d_out;
  float* out_pos_h   = out;
  float* out_neg_h   = out + H_ELEMS;
  float* out_summary = out + 2 * H_ELEMS;
  float* out_pos_seq = out + 2 * H_ELEMS + DOUT;
  float* out_neg_seq = out_pos_seq + SEQ_ELEMS;

  uint32_t* wsu    = (uint32_t*)d_ws;
  float*    sumbuf = (float*)(wsu + W_SUMBUF);
  uint32_t* rowptr = wsu + W_ROWPTR;
  uint32_t* colsrc = wsu + W_COLSRC;
  float*    dinv   = (float*)(wsu + W_DINV);
  uint32_t* rankA  = wsu + W_RANK;
  uint32_t* rankB  = wsu + W_RANK + 50000;
  uint16_t* BT     = (uint16_t*)(wsu + W_BT);
  uint16_t* hwI    = (uint16_t*)(wsu + W_HWI);

  // 1) init (zero + keys + BT transpose)
  wt_init_kernel<<<DIN / 32, 256, 0, stream>>>(W, wsu);

  // 2) degree count + keygen/bucket-hist both sorts
  fusedA_kernel<<<EDGE_BLOCKS + 2 * RS_NB, 1024, 0, stream>>>(ei, wsu);

  // 3) csr scan + bucket scans
  fusedB_kernel<<<3, 1024, 0, stream>>>(wsu);

  // 4) CSR fill + ticket-scatter into buckets
  fusedC_kernel<<<EDGE_BLOCKS + 2 * RS_NB, 1024, 0, stream>>>(ei, wsu);

  // 5) per-bucket rank (both sorts)
  rank_kernel<<<128, 1024, 0, stream>>>(wsu);

  // 6) fused dropout + GEMM + scale/permute/interleave epilogue (both branches)
  dim3 dgrid((N_NODES + 127) / 128, 2);
  dg_kernel<<<dgrid, 256, 0, stream>>>(x, BT, pprob, dinv, rankA, rankB,
                                       out_pos_seq, out_neg_seq, hwI, N_NODES);

  // 7) gather conv (both branches, interleaved reads)
  gcn_gather_kernel<<<N_NODES / 8, 256, 0, stream>>>(hwI, dinv, rowptr, colsrc,
                                                     bias, out_pos_h, out_neg_h);

  // 8) summary
  colsum_sig_kernel<<<(N_NODES + 255) / 256, 128, 0, stream>>>(out_pos_h, sumbuf,
                                                               wsu + W_CNT + 3, out_summary);

  (void)in_sizes; (void)n_in; (void)out_size; (void)ws_size;
}

// Round 19
// 504.604 us; speedup vs baseline: 1.0613x; 1.0613x over previous
//
#include <hip/hip_runtime.h>
#include <stdint.h>

// ---------------- problem constants ----------------
static constexpr int    N_NODES = 50000;
static constexpr int    N_EDGES = 800000;
static constexpr int    DIN     = 512;
static constexpr int    DOUT    = 128;
static constexpr size_t SEQ_ELEMS = (size_t)N_NODES * DIN;   // 25,600,000
static constexpr size_t H_ELEMS   = (size_t)N_NODES * DOUT;  //  6,400,000

static constexpr int RS_NB = 49;          // 49 keygen/scatter tiles x 1024
static constexpr int EDGE_BLOCKS = 782;   // ceil(800000/1024)
static_assert(N_NODES % 8 == 0, "gather grid assumes 8 nodes/block exactly");

typedef __attribute__((ext_vector_type(8))) short bf16x8;
typedef __attribute__((ext_vector_type(4))) float f32x4;
typedef __attribute__((ext_vector_type(4))) unsigned short u16x4;
typedef __attribute__((ext_vector_type(8))) unsigned short u16x8;

// ---------------- workspace layout (u32 word offsets) ----------------
static constexpr size_t W_HDR    = 0;         // 16 (keys at [4..7])
static constexpr size_t W_DEGCNT = 16;        // 50000
static constexpr size_t W_CURSOR = 50016;     // 50000
static constexpr size_t W_SUMBUF = 100016;    // 128 (float)
static constexpr size_t W_CNT    = 100144;    // 8 (cnt[3]=colsum tail)
static constexpr size_t W_ZEND   = 100152;
static constexpr size_t W_ROWPTR = 175416;    // 50001 (+pad)
static constexpr size_t W_COLSRC = 225420;    // 800000
static constexpr size_t W_DINV   = 1025420;   // 50000 (float)
static constexpr size_t W_KEYS   = 1075420;   // per sort s: keys_in +s*100000, bucket-keys +s*100000+50000
static constexpr size_t W_VALS   = 1275420;   // per sort s: bucket-vals +s*50000
static constexpr size_t W_RANK   = 1475420;   // rank[s][50000]
static constexpr size_t W_BT     = 1625420;   // 128x512 bf16 = 32768 u32 (16B aligned)
static constexpr size_t W_HWI    = 1658188;   // interleaved hw: [50000][256] bf16
static constexpr size_t W_BHIST  = 8058188;   // 2 x 65536 bucket hist
static constexpr size_t W_BOFF   = 8189260;   // 2 x 65536 bucket start (preserved)
static constexpr size_t W_BCUR   = 8320332;   // 2 x 65536 bucket cursor (ticketed)

// ---------------- helpers ----------------
__device__ __forceinline__ uint16_t f2bf(float f) {
  uint32_t u = __float_as_uint(f);
  return (uint16_t)((u + 0x7FFFu + ((u >> 16) & 1u)) >> 16);
}
__device__ __forceinline__ float b2f(uint16_t h) {
  return __uint_as_float(((uint32_t)h) << 16);
}
__device__ __forceinline__ uint32_t rotl32(uint32_t x, int r) {
  return (x << r) | (x >> (32 - r));
}

__device__ __forceinline__ void threefry2x32(uint32_t k0, uint32_t k1,
                                             uint32_t x0, uint32_t x1,
                                             uint32_t& o0, uint32_t& o1) {
  uint32_t ks0 = k0, ks1 = k1, ks2 = k0 ^ k1 ^ 0x1BD11BDAu;
  x0 += ks0; x1 += ks1;
#define TF_ROUND(r) { x0 += x1; x1 = rotl32(x1, (r)); x1 ^= x0; }
  TF_ROUND(13) TF_ROUND(15) TF_ROUND(26) TF_ROUND(6)
  x0 += ks1; x1 += ks2 + 1u;
  TF_ROUND(17) TF_ROUND(29) TF_ROUND(16) TF_ROUND(24)
  x0 += ks2; x1 += ks0 + 2u;
  TF_ROUND(13) TF_ROUND(15) TF_ROUND(26) TF_ROUND(6)
  x0 += ks0; x1 += ks1 + 3u;
  TF_ROUND(17) TF_ROUND(29) TF_ROUND(16) TF_ROUND(24)
  x0 += ks1; x1 += ks2 + 4u;
  TF_ROUND(13) TF_ROUND(15) TF_ROUND(26) TF_ROUND(6)
  x0 += ks2; x1 += ks0 + 5u;
#undef TF_ROUND
  o0 = x0; o1 = x1;
}

__device__ __forceinline__ uint32_t randbits32(uint32_t k0, uint32_t k1, uint32_t ctr) {
  uint32_t a, b;
  threefry2x32(k0, k1, 0u, ctr, a, b);
  return a ^ b;
}

// ---------------- init: zero accumulators + bucket hists + keys + W->BT ----------------
__global__ void __launch_bounds__(256) wt_init_kernel(const float* __restrict__ W,
                                                      uint32_t* __restrict__ wsu) {
  {
    int gid = blockIdx.x * 256 + threadIdx.x;  // 4096 threads
    for (size_t i = W_DEGCNT + gid; i < W_ZEND; i += 4096) wsu[i] = 0u;
    for (size_t i = W_BHIST + gid; i < W_BHIST + 131072; i += 4096) wsu[i] = 0u;
  }
  if (blockIdx.x == 0 && threadIdx.x == 0) {
    uint32_t k3a, k3b, ra, rb, s1a, s1b, s2a, s2b;
    threefry2x32(0u, 1u, 0u, 2u, k3a, k3b);   // split(key(1),3)[2]
    threefry2x32(k3a, k3b, 0u, 0u, ra, rb);   // round1 carry key
    threefry2x32(k3a, k3b, 0u, 1u, s1a, s1b); // round1 subkey
    threefry2x32(ra, rb, 0u, 1u, s2a, s2b);   // round2 subkey
    wsu[4] = s1a; wsu[5] = s1b; wsu[6] = s2a; wsu[7] = s2b;
  }
  uint16_t* BT = (uint16_t*)(wsu + W_BT);
  __shared__ float tile[32][129];
  int k0 = blockIdx.x * 32;
  int t = threadIdx.x;
  for (int i = t; i < 32 * 128; i += 256) {
    int k = i >> 7, n = i & 127;
    tile[k][n] = W[(size_t)(k0 + k) * DOUT + n];
  }
  __syncthreads();
  for (int i = t; i < 32 * 128; i += 256) {
    int n = i >> 5, k = i & 31;
    BT[(size_t)n * DIN + k0 + k] = f2bf(tile[k][n]);
  }
}

// ---------------- fusedA: degree count + keygen/bucket-hist for both sorts ----------------
__global__ void __launch_bounds__(1024) fusedA_kernel(const int* __restrict__ ei,
                                                      uint32_t* __restrict__ wsu) {
  int b = blockIdx.x;
  if (b < EDGE_BLOCKS) {
    int e = b * 1024 + threadIdx.x;
    if (e < N_EDGES) atomicAdd(&wsu[W_DEGCNT + ei[N_EDGES + e]], 1u);
  } else {
    int sb = b - EDGE_BLOCKS, s = sb / RS_NB, bb = sb % RS_NB;
    int p = bb * 1024 + threadIdx.x;
    if (p < N_NODES) {
      uint32_t kv = randbits32(wsu[4 + 2 * s], wsu[5 + 2 * s], (uint32_t)p);
      wsu[W_KEYS + (size_t)s * 100000 + p] = kv;
      atomicAdd(&wsu[W_BHIST + (size_t)s * 65536 + (kv >> 16)], 1u);
    }
  }
}

// ---------------- fusedB: csr scan+dinv (b0) + bucket scans (b1,b2) ----------------
__global__ void __launch_bounds__(1024) fusedB_kernel(uint32_t* __restrict__ wsu) {
  __shared__ uint32_t sc[1024];
  int b = blockIdx.x, t = threadIdx.x;
  if (b == 0) {
    int c0 = t * 49, c1 = c0 + 49;
    if (c0 > N_NODES) c0 = N_NODES;
    if (c1 > N_NODES) c1 = N_NODES;
    float* dinv = (float*)(wsu + W_DINV);
    uint32_t sum = 0;
    for (int c = c0; c < c1; ++c) {
      uint32_t v = wsu[W_DEGCNT + c];
      dinv[c] = __frsqrt_rn((float)(v + 1u));
      sum += v;
    }
    sc[t] = sum;
    __syncthreads();
    for (int off = 1; off < 1024; off <<= 1) {
      uint32_t xx = (t >= off) ? sc[t - off] : 0u;
      __syncthreads();
      sc[t] += xx;
      __syncthreads();
    }
    uint32_t run = sc[t] - sum;
    for (int c = c0; c < c1; ++c) {
      uint32_t h = wsu[W_DEGCNT + c];
      wsu[W_ROWPTR + c] = run;
      run += h;
    }
    if (t == 0) wsu[W_ROWPTR + N_NODES] = (uint32_t)N_EDGES;
  } else {
    int s = b - 1;
    const uint32_t* bh = wsu + W_BHIST + (size_t)s * 65536;
    uint32_t* boff = wsu + W_BOFF + (size_t)s * 65536;
    uint32_t* bcur = wsu + W_BCUR + (size_t)s * 65536;
    int c0 = t * 64;
    uint32_t sum = 0;
    for (int j = 0; j < 64; ++j) sum += bh[c0 + j];
    sc[t] = sum;
    __syncthreads();
    for (int off = 1; off < 1024; off <<= 1) {
      uint32_t xx = (t >= off) ? sc[t - off] : 0u;
      __syncthreads();
      sc[t] += xx;
      __syncthreads();
    }
    uint32_t run = sc[t] - sum;
    for (int j = 0; j < 64; ++j) {
      uint32_t h = bh[c0 + j];
      boff[c0 + j] = run;
      bcur[c0 + j] = run;
      run += h;
    }
  }
}

// ---------------- fusedC: CSR fill + ticket-scatter into buckets ----------------
__global__ void __launch_bounds__(1024) fusedC_kernel(const int* __restrict__ ei,
                                                      uint32_t* __restrict__ wsu) {
  int b = blockIdx.x;
  if (b < EDGE_BLOCKS) {
    int e = b * 1024 + threadIdx.x;
    if (e < N_EDGES) {
      int src = ei[e], dst = ei[N_EDGES + e];
      uint32_t pos = wsu[W_ROWPTR + dst] + atomicAdd(&wsu[W_CURSOR + dst], 1u);
      wsu[W_COLSRC + pos] = (uint32_t)src;
    }
  } else {
    int sb = b - EDGE_BLOCKS, s = sb / RS_NB, bb = sb % RS_NB;
    int p = bb * 1024 + threadIdx.x;
    if (p < N_NODES) {
      uint32_t kv = wsu[W_KEYS + (size_t)s * 100000 + p];
      uint32_t pos = atomicAdd(&wsu[W_BCUR + (size_t)s * 65536 + (kv >> 16)], 1u);
      if (pos < (uint32_t)N_NODES) {
        wsu[W_KEYS + (size_t)s * 100000 + 50000 + pos] = kv;  // bucket keys
        wsu[W_VALS + (size_t)s * 50000 + pos] = (uint32_t)p;  // bucket vals
      }
    }
  }
}

// ---------------- rank: per-bucket (key,idx) compare -> exact stable ranks ----------------
__global__ void __launch_bounds__(1024) rank_kernel(uint32_t* __restrict__ wsu) {
  int gid = blockIdx.x * 1024 + threadIdx.x;  // 131072 threads = 2 x 65536 buckets
  int s = gid >> 16;
  int bkt = gid & 65535;
  uint32_t start = wsu[W_BOFF + (size_t)s * 65536 + bkt];
  uint32_t end   = wsu[W_BCUR + (size_t)s * 65536 + bkt];
  if (end > (uint32_t)N_NODES) end = (uint32_t)N_NODES;
  if (end <= start) return;
  uint32_t c = end - start;
  if (c > 64u) c = 64u;  // defensive cap
  const uint32_t* bk = wsu + W_KEYS + (size_t)s * 100000 + 50000;
  const uint32_t* bv = wsu + W_VALS + (size_t)s * 50000;
  uint32_t* rank = wsu + W_RANK + (size_t)s * 50000;
  for (uint32_t i = 0; i < c; ++i) {
    uint32_t ki = bk[start + i], vi = bv[start + i];
    uint32_t rib = 0;
    for (uint32_t j = 0; j < c; ++j) {
      uint32_t kj = bk[start + j], vj = bv[start + j];
      rib += (kj < ki) || (kj == ki && vj < vi);
    }
    if (vi < (uint32_t)N_NODES && start + rib < (uint32_t)N_NODES)
      rank[vi] = start + rib;
  }
}

// ---------------- fused dropout + MFMA bf16 GEMM (swizzled LDS, NT seq stores) ----------
__global__ void __launch_bounds__(256) dg_kernel(const float* __restrict__ x,
                                                 const uint16_t* __restrict__ BT,
                                                 const float* __restrict__ pprob,
                                                 const float* __restrict__ dinv,
                                                 const uint32_t* __restrict__ rankA,
                                                 const uint32_t* __restrict__ rankB,
                                                 float* __restrict__ seq_pos,
                                                 float* __restrict__ seq_neg,
                                                 uint16_t* __restrict__ hwI, int M) {
  __shared__ __align__(16) uint16_t ldsA[64 * 64];
  __shared__ __align__(16) uint16_t ldsB[128 * 64];
  const int which = blockIdx.y;
  float* seq = which ? seq_neg : seq_pos;

  uint32_t kk0, kk1;
  threefry2x32(0u, 1u, 0u, (uint32_t)which, kk0, kk1);  // split(key(1),3)[which]
  const float p = pprob[0];
  const float keep_p = 1.0f - p;
  const float scale  = 1.0f / keep_p;
  uint32_t Tint = (uint32_t)ceilf(keep_p * 8388608.0f);
  uint32_t Tu = (Tint >= (1u << 23)) ? 0xFFFFFFFFu : (Tint << 9);

  const int tid  = threadIdx.x;
  const int lane = tid & 63;
  const int w    = tid >> 6;
  const int wr   = w >> 1, wc = w & 1;
  const int m0   = blockIdx.x * 64;
  const int l15  = lane & 15, l4 = lane >> 4;
  const int lr   = lane >> 3;
  const int lk_swz = (((lane & 7) ^ (lane >> 3)) * 8);  // pre-swizzled source block

  f32x4 acc[2][4] = {};

  for (int k0 = 0; k0 < DIN; k0 += 64) {
    // B tile first (pinned oldest in vmcnt order); source pre-swizzled per lane.
#pragma unroll
    for (int s = 0; s < 4; ++s) {
      int nbase = w * 32 + s * 8;  // nbase % 8 == 0 -> row&7 == lane>>3
      const uint16_t* gp = BT + (size_t)(nbase + lr) * DIN + k0 + lk_swz;
      __builtin_amdgcn_global_load_lds(
          (const __attribute__((address_space(1))) void*)gp,
          (__attribute__((address_space(3))) void*)(ldsB + nbase * 64), 16, 0, 0);
    }
    __builtin_amdgcn_sched_barrier(0);  // keep B-loads the 4 oldest VMEM ops
#pragma unroll
    for (int i = 0; i < 4; ++i) {
      int idx = tid + i * 256;
      int row = idx >> 4, q = idx & 15;
      int grow = m0 + row;
      int crow = (grow < M) ? grow : (M - 1);  // tail rows duplicate row M-1 (benign)
      float4 v = *reinterpret_cast<const float4*>(x + (size_t)crow * DIN + k0 + q * 4);
      float r[4] = {v.x, v.y, v.z, v.w};
      uint32_t cbase = (uint32_t)crow * DIN + k0 + q * 4;
#pragma unroll
      for (int j = 0; j < 4; ++j) {
        uint32_t bits = randbits32(kk0, kk1, cbase + j);
        r[j] = (bits < Tu) ? r[j] * scale : 0.0f;
      }
      // NT store (ext-vector type): seq is never re-read on device
      f32x4 rv;
      rv.x = r[0]; rv.y = r[1]; rv.z = r[2]; rv.w = r[3];
      __builtin_nontemporal_store(rv,
          reinterpret_cast<f32x4*>(seq + (size_t)crow * DIN + k0 + q * 4));
      uint32_t u0 = __float_as_uint(r[0]), u1 = __float_as_uint(r[1]);
      uint32_t lo = (u0 >> 16) | (u1 & 0xFFFF0000u);
      u0 = __float_as_uint(r[2]); u1 = __float_as_uint(r[3]);
      uint32_t hi = (u0 >> 16) | (u1 & 0xFFFF0000u);
      // swizzled ds_write: block (q>>1) -> (q>>1)^(row&7), keep 8B half (q&1)
      int sblk = (q >> 1) ^ (row & 7);
      *reinterpret_cast<uint2*>(&ldsA[row * 64 + sblk * 8 + (q & 1) * 4]) = make_uint2(lo, hi);
    }
    asm volatile("s_waitcnt vmcnt(4) lgkmcnt(0)" ::: "memory");
    __builtin_amdgcn_s_barrier();
    __builtin_amdgcn_sched_barrier(0);  // rule #18: no hoisting above the barrier
#pragma unroll
    for (int kk = 0; kk < 2; ++kk) {
      bf16x8 afr[2], bfr[4];
#pragma unroll
      for (int f = 0; f < 2; ++f) {
        int ra = wr * 32 + f * 16 + l15;
        int bp = (kk * 4 + l4) ^ (ra & 7);
        afr[f] = *reinterpret_cast<const bf16x8*>(ldsA + ra * 64 + bp * 8);
      }
#pragma unroll
      for (int f = 0; f < 4; ++f) {
        int rb = wc * 64 + f * 16 + l15;
        int bp = (kk * 4 + l4) ^ (rb & 7);
        bfr[f] = *reinterpret_cast<const bf16x8*>(ldsB + rb * 64 + bp * 8);
      }
#pragma unroll
      for (int fm = 0; fm < 2; ++fm)
#pragma unroll
        for (int fn = 0; fn < 4; ++fn)
          acc[fm][fn] = __builtin_amdgcn_mfma_f32_16x16x32_bf16(afr[fm], bfr[fn], acc[fm][fn], 0, 0, 0);
    }
    __builtin_amdgcn_s_barrier();  // LDS reuse guard
  }
#pragma unroll
  for (int fm = 0; fm < 2; ++fm) {
#pragma unroll
    for (int r = 0; r < 4; ++r) {
      int row = m0 + wr * 32 + fm * 16 + l4 * 4 + r;
      if (row < M) {
        uint32_t slot = (uint32_t)row;
        if (which) {
          uint32_t r1 = rankA[row];
          slot = (r1 < (uint32_t)N_NODES) ? rankB[r1] : 0u;
          if (slot >= (uint32_t)N_NODES) slot = 0u;
        }
        float sc = dinv[slot];
        uint16_t* cp = hwI + (size_t)slot * 256 + which * 128 + wc * 64 + l15;
#pragma unroll
        for (int fn = 0; fn < 4; ++fn)
          cp[fn * 16] = f2bf(acc[fm][fn][r] * sc);
      }
    }
  }
}

// ---------------- gather conv: interleaved hwI rows, 16B/lane, 8-edge unroll ----------
__global__ void __launch_bounds__(256) gcn_gather_kernel(const uint16_t* __restrict__ hwI,
                                                         const float* __restrict__ dinv,
                                                         const uint32_t* __restrict__ rowptr,
                                                         const uint32_t* __restrict__ colsrc,
                                                         const float* __restrict__ bias,
                                                         float* __restrict__ out_pos,
                                                         float* __restrict__ out_neg) {
  const int t = threadIdx.x;
  int node = blockIdx.x * 8 + (t >> 5);  // N_NODES % 8 == 0
  int lane32 = t & 31;
  int c8 = (lane32 & 15) * 8;
  int half = lane32 >> 4;                // 0 = pos, 1 = neg
  uint32_t e0 = rowptr[node], e1 = rowptr[node + 1];
  float a0 = 0.f, a1 = 0.f, a2 = 0.f, a3 = 0.f, a4 = 0.f, a5 = 0.f, a6 = 0.f, a7 = 0.f;
  uint32_t e = e0;
  for (; e + 8 <= e1; e += 8) {
    uint32_t ss[8];
#pragma unroll
    for (int j = 0; j < 8; ++j) ss[j] = colsrc[e + j];
    u16x8 vv[8];
#pragma unroll
    for (int j = 0; j < 8; ++j)
      vv[j] = *reinterpret_cast<const u16x8*>(hwI + (size_t)ss[j] * 256 + lane32 * 8);
#pragma unroll
    for (int j = 0; j < 8; ++j) {
      a0 += b2f(vv[j][0]); a1 += b2f(vv[j][1]); a2 += b2f(vv[j][2]); a3 += b2f(vv[j][3]);
      a4 += b2f(vv[j][4]); a5 += b2f(vv[j][5]); a6 += b2f(vv[j][6]); a7 += b2f(vv[j][7]);
    }
  }
  for (; e < e1; ++e) {
    uint32_t s = colsrc[e];
    u16x8 v = *reinterpret_cast<const u16x8*>(hwI + (size_t)s * 256 + lane32 * 8);
    a0 += b2f(v[0]); a1 += b2f(v[1]); a2 += b2f(v[2]); a3 += b2f(v[3]);
    a4 += b2f(v[4]); a5 += b2f(v[5]); a6 += b2f(v[6]); a7 += b2f(v[7]);
  }
  u16x8 sv = *reinterpret_cast<const u16x8*>(hwI + (size_t)node * 256 + lane32 * 8);
  float dn = dinv[node];
  float4 b0 = *reinterpret_cast<const float4*>(bias + c8);
  float4 b1 = *reinterpret_cast<const float4*>(bias + c8 + 4);
  f32x4 o0, o1;
  o0.x = fmaxf(dn * (a0 + b2f(sv[0])) + b0.x, 0.0f);
  o0.y = fmaxf(dn * (a1 + b2f(sv[1])) + b0.y, 0.0f);
  o0.z = fmaxf(dn * (a2 + b2f(sv[2])) + b0.z, 0.0f);
  o0.w = fmaxf(dn * (a3 + b2f(sv[3])) + b0.w, 0.0f);
  o1.x = fmaxf(dn * (a4 + b2f(sv[4])) + b1.x, 0.0f);
  o1.y = fmaxf(dn * (a5 + b2f(sv[5])) + b1.y, 0.0f);
  o1.z = fmaxf(dn * (a6 + b2f(sv[6])) + b1.z, 0.0f);
  o1.w = fmaxf(dn * (a7 + b2f(sv[7])) + b1.w, 0.0f);
  float* dst = (half ? out_neg : out_pos) + (size_t)node * DOUT + c8;
  if (half) {
    // out_neg never re-read on device -> NT store
    __builtin_nontemporal_store(o0, reinterpret_cast<f32x4*>(dst));
    __builtin_nontemporal_store(o1, reinterpret_cast<f32x4*>(dst + 4));
  } else {
    *reinterpret_cast<f32x4*>(dst)     = o0;
    *reinterpret_cast<f32x4*>(dst + 4) = o1;
  }
}

// ---------------- summary: colsum (196 blocks) + last-block sigmoid ----------------
__global__ void __launch_bounds__(128) colsum_sig_kernel(const float* __restrict__ ph,
                                                         float* __restrict__ sumbuf,
                                                         uint32_t* __restrict__ counter,
                                                         float* __restrict__ outs) {
  int c = threadIdx.x;  // 0..127
  int r0 = blockIdx.x * 256;
  int r1 = r0 + 256; if (r1 > N_NODES) r1 = N_NODES;
  float s = 0.0f;
  for (int r = r0; r < r1; ++r) s += ph[(size_t)r * DOUT + c];
  atomicAdd(&sumbuf[c], s);
  __threadfence();
  __syncthreads();
  __shared__ uint32_t lastflag;
  if (c == 0) lastflag = atomicAdd(counter, 1u);
  __syncthreads();
  if (lastflag == gridDim.x - 1) {
    __threadfence();
    float m = atomicAdd(&sumbuf[c], 0.0f) * (1.0f / (float)N_NODES);
    outs[c] = 1.0f / (1.0f + expf(-m));
  }
}

// ---------------- launch ----------------
extern "C" void kernel_launch(void* const* d_in, const int* in_sizes, int n_in,
                              void* d_out, int out_size, void* d_ws, size_t ws_size,
                              hipStream_t stream) {
  const float* x     = (const float*)d_in[0];
  const int*   ei    = (const int*)d_in[1];
  const float* W     = (const float*)d_in[2];
  const float* bias  = (const float*)d_in[3];
  const float* pprob = (const float*)d_in[4];

  float* out = (float*)d_out;
  float* out_pos_h   = out;
  float* out_neg_h   = out + H_ELEMS;
  float* out_summary = out + 2 * H_ELEMS;
  float* out_pos_seq = out + 2 * H_ELEMS + DOUT;
  float* out_neg_seq = out_pos_seq + SEQ_ELEMS;

  uint32_t* wsu    = (uint32_t*)d_ws;
  float*    sumbuf = (float*)(wsu + W_SUMBUF);
  uint32_t* rowptr = wsu + W_ROWPTR;
  uint32_t* colsrc = wsu + W_COLSRC;
  float*    dinv   = (float*)(wsu + W_DINV);
  uint32_t* rankA  = wsu + W_RANK;
  uint32_t* rankB  = wsu + W_RANK + 50000;
  uint16_t* BT     = (uint16_t*)(wsu + W_BT);
  uint16_t* hwI    = (uint16_t*)(wsu + W_HWI);

  // 1) init (zero + keys + BT transpose)
  wt_init_kernel<<<DIN / 32, 256, 0, stream>>>(W, wsu);

  // 2) degree count + keygen/bucket-hist both sorts
  fusedA_kernel<<<EDGE_BLOCKS + 2 * RS_NB, 1024, 0, stream>>>(ei, wsu);

  // 3) csr scan + bucket scans
  fusedB_kernel<<<3, 1024, 0, stream>>>(wsu);

  // 4) CSR fill + ticket-scatter into buckets
  fusedC_kernel<<<EDGE_BLOCKS + 2 * RS_NB, 1024, 0, stream>>>(ei, wsu);

  // 5) per-bucket rank (both sorts)
  rank_kernel<<<128, 1024, 0, stream>>>(wsu);

  // 6) fused dropout + GEMM + scale/permute/interleave epilogue (both branches)
  dim3 dgrid((N_NODES + 63) / 64, 2);
  dg_kernel<<<dgrid, 256, 0, stream>>>(x, BT, pprob, dinv, rankA, rankB,
                                       out_pos_seq, out_neg_seq, hwI, N_NODES);

  // 7) gather conv (both branches, interleaved reads)
  gcn_gather_kernel<<<N_NODES / 8, 256, 0, stream>>>(hwI, dinv, rowptr, colsrc,
                                                     bias, out_pos_h, out_neg_h);

  // 8) summary
  colsum_sig_kernel<<<(N_NODES + 255) / 256, 128, 0, stream>>>(out_pos_h, sumbuf,
                                                               wsu + W_CNT + 3, out_summary);

  (void)in_sizes; (void)n_in; (void)out_size; (void)ws_size;
}